// Round 14
// baseline (223.207 us; speedup 1.0000x reference)
//
#include <hip/hip_runtime.h>
#include <stdint.h>

// WhaleAttention: B=2 N=2048 C=1024 H=16 D=64
// R14: (1) split-K flash: KV halved per block -> 1024 blocks, 3 blocks/CU = 6 waves/SIMD;
// partials (O,m,l f32) -> dead pre-gap; exact combine kernel. (2) P-pack via inline-asm
// v_cvt_pk_bf16_f32. (3) post_qk+post_vp merged into one launch.

typedef short short8 __attribute__((ext_vector_type(8)));
typedef float f32x4 __attribute__((ext_vector_type(4)));
typedef unsigned short us4 __attribute__((ext_vector_type(4)));
typedef unsigned int u32x4 __attribute__((ext_vector_type(4)));
typedef unsigned short u16;
typedef unsigned int u32;

#define NB 2
#define NN 2048
#define NC 1024
#define NH 16
#define ND 64

__device__ __forceinline__ u16 f2bf(float f) {
    unsigned int u = __float_as_uint(f);
    u += 0x7fffu + ((u >> 16) & 1u);
    return (u16)(u >> 16);
}
__device__ __forceinline__ float bf2f(u16 v) {
    return __uint_as_float(((u32)v) << 16);
}
__device__ __forceinline__ u32 cvtpk_bf16(float lo, float hi) {
    u32 d;
    asm("v_cvt_pk_bf16_f32 %0, %1, %2" : "=v"(d) : "v"(lo), "v"(hi));
    return d;
}

__device__ __forceinline__ int swzc(int row, int c) {
    return (((c >> 3) ^ (row & 7)) << 3) | (c & 7);
}

__device__ __forceinline__ void gload16(const void* g, void* l) {
    __builtin_amdgcn_global_load_lds(
        (const __attribute__((address_space(1))) unsigned int*)g,
        (__attribute__((address_space(3))) unsigned int*)l, 16, 0, 0);
}

// ---------------- casts (merged) ----------------
__global__ __launch_bounds__(256) void cast_xpos(const float* __restrict__ x,
                                                 const float* __restrict__ pos,
                                                 u16* __restrict__ dx,
                                                 u16* __restrict__ dpos) {
    const float* s = blockIdx.y ? pos : x;
    u16* d = blockIdx.y ? dpos : dx;
    int i = blockIdx.x * 256 + threadIdx.x;
    float4 f = reinterpret_cast<const float4*>(s)[i];
    us4 o;
    o[0] = f2bf(f.x); o[1] = f2bf(f.y); o[2] = f2bf(f.z); o[3] = f2bf(f.w);
    reinterpret_cast<us4*>(d)[i] = o;
}

__global__ __launch_bounds__(256) void cast_w(const float* __restrict__ w0,
                                              const float* __restrict__ w1,
                                              const float* __restrict__ w2,
                                              const float* __restrict__ w3,
                                              const float* __restrict__ w4,
                                              u16* __restrict__ dst) {
    int z = blockIdx.y;
    const float* s = (z == 0) ? w0 : (z == 1) ? w1 : (z == 2) ? w2 : (z == 3) ? w3 : w4;
    u16* d = dst + (size_t)z * 1048576;
    int i = blockIdx.x * 256 + threadIdx.x;
    float4 f = reinterpret_cast<const float4*>(s)[i];
    us4 o;
    o[0] = f2bf(f.x); o[1] = f2bf(f.y); o[2] = f2bf(f.z); o[3] = f2bf(f.w);
    reinterpret_cast<us4*>(d)[i] = o;
}

// ---------------- GEMM C = A @ W^T (+bias); gload_lds + dbuf; OT = float|u16(bf16) ----------------
__device__ __forceinline__ void gemm_stage(const u16* __restrict__ A,
                                           const u16* __restrict__ W,
                                           u16* As, u16* Bs,
                                           int m0, int n0, int kk, int w, int lane) {
    int lr4 = lane >> 2, lc8 = (lane & 3) * 8;
#pragma unroll
    for (int i = 0; i < 2; i++) {
        int rbase = w * 32 + i * 16;
        gload16(A + (size_t)(m0 + rbase + lr4) * 1024 + kk + lc8, As + rbase * 32);
        gload16(W + (size_t)(n0 + rbase + lr4) * 1024 + kk + lc8, Bs + rbase * 32);
    }
}

template <typename OT>
__device__ __forceinline__ void gemm_bt_body(const u16* __restrict__ A,
                                             const u16* __restrict__ W,
                                             OT* __restrict__ out,
                                             const float* __restrict__ bias,
                                             int m0, int n0) {
    __shared__ u16 As[2][128 * 32];
    __shared__ u16 Bs[2][128 * 32];
    int t = threadIdx.x, lane = t & 63, w = t >> 6;
    int wm = (w >> 1) * 64, wn = (w & 1) * 64;
    int lr = lane & 15, lg = lane >> 4;
    f32x4 acc[4][4] = {};

    gemm_stage(A, W, As[0], Bs[0], m0, n0, 0, w, lane);
    __syncthreads();
    int cur = 0;
    for (int kt = 0; kt < 32; kt++) {
        if (kt < 31)
            gemm_stage(A, W, As[cur ^ 1], Bs[cur ^ 1], m0, n0, (kt + 1) * 32, w, lane);
        const u16* Ac = As[cur];
        const u16* Bc = Bs[cur];
        short8 af[4], bw[4];
#pragma unroll
        for (int mt = 0; mt < 4; mt++)
            af[mt] = *reinterpret_cast<const short8*>(Ac + (wm + mt * 16 + lr) * 32 + lg * 8);
#pragma unroll
        for (int nt = 0; nt < 4; nt++)
            bw[nt] = *reinterpret_cast<const short8*>(Bc + (wn + nt * 16 + lr) * 32 + lg * 8);
#pragma unroll
        for (int mt = 0; mt < 4; mt++)
#pragma unroll
            for (int nt = 0; nt < 4; nt++)
                acc[mt][nt] = __builtin_amdgcn_mfma_f32_16x16x32_bf16(af[mt], bw[nt], acc[mt][nt], 0, 0, 0);
        __syncthreads();
        cur ^= 1;
    }
#pragma unroll
    for (int mt = 0; mt < 4; mt++) {
#pragma unroll
        for (int nt = 0; nt < 4; nt++) {
            int c = n0 + wn + nt * 16 + lr;
            float badd = bias ? bias[c] : 0.0f;
            int r = m0 + wm + mt * 16 + lg * 4;
#pragma unroll
            for (int rg = 0; rg < 4; rg++) {
                float val = acc[mt][nt][rg] + badd;
                if constexpr (__is_same(OT, float))
                    out[(size_t)(r + rg) * 1024 + c] = val;
                else
                    out[(size_t)(r + rg) * 1024 + c] = f2bf(val);
            }
        }
    }
}

// z=0:q(bq) 1:k(bk) 2:v(bv) 3:p(none, A=pos); writes bf16 pre
__global__ __launch_bounds__(256) void proj_gemm(const u16* __restrict__ xbf,
                                                 const u16* __restrict__ posbf,
                                                 const u16* __restrict__ Wbase,
                                                 u16* __restrict__ prebase,
                                                 const float* __restrict__ bq,
                                                 const float* __restrict__ bk,
                                                 const float* __restrict__ bv) {
    int z = blockIdx.z;
    const u16* A = (z == 3) ? posbf : xbf;
    const u16* W = Wbase + (size_t)z * 1048576;
    u16* out = prebase + (size_t)z * 4194304;
    const float* bias = (z == 0) ? bq : ((z == 1) ? bk : ((z == 2) ? bv : (const float*)nullptr));
    gemm_bt_body<u16>(A, W, out, bias, blockIdx.y * 128, blockIdx.x * 128);
}

__global__ __launch_bounds__(256) void out_gemm(const u16* __restrict__ ctx,
                                                const u16* __restrict__ Wo,
                                                float* __restrict__ out,
                                                const float* __restrict__ bo) {
    gemm_bt_body<float>(ctx, Wo, out, bo, blockIdx.y * 128, blockIdx.x * 128);
}

// ---------------- fused posts: y=0 LN(q), y=1 LN(k), y=2 v->Vt + p->KK hi ----------------
__global__ __launch_bounds__(256) void post_fused(const u16* __restrict__ prebase,
                                                  const float* __restrict__ qw, const float* __restrict__ qb,
                                                  const float* __restrict__ kw, const float* __restrict__ kb,
                                                  const float* __restrict__ pbu, const float* __restrict__ pbv,
                                                  u16* __restrict__ QQ, u16* __restrict__ KK,
                                                  u16* __restrict__ Vt) {
    __shared__ u16 tile[64][68];
    const float QSC = 0.125f * 1.44269504089f;
    int yv = blockIdx.y;
    if (yv < 2) {
        int isq = (yv == 0);
        const u16* pre = prebase + (isq ? 0 : (size_t)4194304);
        const float* lw = isq ? qw : kw;
        const float* lb = isq ? qb : kb;
        int wv = threadIdx.x >> 6, lane = threadIdx.x & 63;
        int row = blockIdx.x * 4 + wv;   // 0..4095
        int b = row >> 11, n = row & 2047;
        const u16* pr = pre + (size_t)row * 1024;
        float vals[16];
        float s = 0.f, s2 = 0.f;
#pragma unroll
        for (int i = 0; i < 2; i++) {
            short8 v8 = *reinterpret_cast<const short8*>(pr + i * 512 + lane * 8);
#pragma unroll
            for (int j = 0; j < 8; j++) {
                float f = bf2f((u16)v8[j]);
                vals[i * 8 + j] = f;
                s += f; s2 += f * f;
            }
        }
#pragma unroll
        for (int m = 1; m < 64; m <<= 1) { s += __shfl_xor(s, m); s2 += __shfl_xor(s2, m); }
        float mean = s * (1.f / 1024.f);
        float var = s2 * (1.f / 1024.f) - mean * mean;
        float inv = rsqrtf(var + 1e-6f);
#pragma unroll
        for (int i = 0; i < 2; i++) {
            int c0 = i * 512 + lane * 8;
            int h = c0 >> 6, d0 = c0 & 63;
            size_t base = ((size_t)(b * NH + h) * NN + n) * 128;
            if (isq) {
                short8 o0, o1;
#pragma unroll
                for (int j = 0; j < 8; j++) {
                    float xn = (vals[i * 8 + j] - mean) * inv * lw[c0 + j] + lb[c0 + j];
                    o0[j] = (short)f2bf((xn + pbu[h * 64 + d0 + j]) * QSC);
                    o1[j] = (short)f2bf((xn + pbv[h * 64 + d0 + j]) * QSC);
                }
                *reinterpret_cast<short8*>(QQ + base + swzc(n, d0)) = o0;
                *reinterpret_cast<short8*>(QQ + base + swzc(n, d0 + 64)) = o1;
            } else {
                short8 o0;
#pragma unroll
                for (int j = 0; j < 8; j++) {
                    float xn = (vals[i * 8 + j] - mean) * inv * lw[c0 + j] + lb[c0 + j];
                    o0[j] = (short)f2bf(xn);
                }
                *reinterpret_cast<short8*>(KK + base + swzc(n, d0)) = o0;
            }
        }
    } else {
        const u16* vpre = prebase + (size_t)2 * 4194304;
        const u16* ppre = prebase + (size_t)3 * 4194304;
        int bh = blockIdx.x & 31;
        int b = bh >> 4, h = bh & 15;
        int n0 = (blockIdx.x >> 5) * 64;
        int t = threadIdx.x, lane = t & 63, w = t >> 6;
        int nr = t >> 2;
#pragma unroll
        for (int j = 0; j < 2; j++) {
            int d8 = (t & 3) * 16 + j * 8;
            int n = n0 + nr;
            size_t goff = ((size_t)(b * NN + n)) * 1024 + h * 64 + d8;
            short8 v8 = *reinterpret_cast<const short8*>(vpre + goff);
            us4 lo, hi;
#pragma unroll
            for (int jj = 0; jj < 4; jj++) { lo[jj] = (u16)v8[jj]; hi[jj] = (u16)v8[jj + 4]; }
            *reinterpret_cast<us4*>(&tile[nr][d8]) = lo;
            *reinterpret_cast<us4*>(&tile[nr][d8 + 4]) = hi;
            short8 p8 = *reinterpret_cast<const short8*>(ppre + goff);
            *reinterpret_cast<short8*>(KK + ((size_t)(b * NH + h) * NN + n) * 128 + swzc(n, 64 + d8)) = p8;
        }
        __syncthreads();
        size_t vbase = (size_t)(b * NH + h) * 64 * NN;
        int n = n0 + lane;
#pragma unroll
        for (int j = 0; j < 16; j++) {
            int d = w + j * 4;
            int nsw = (n & ~63) | ((((n >> 3) & 7) ^ (d & 7)) << 3) | (n & 7);
            Vt[vbase + (size_t)d * NN + nsw] = tile[lane][d];
        }
    }
}

// ---------------- flash attention split-K: 1024 blocks, each does 16 KV tiles ----------------
__global__ __launch_bounds__(512, 6) void flash_attn(const u16* __restrict__ QQ,
                                                     const u16* __restrict__ KK,
                                                     const u16* __restrict__ Vt,
                                                     float* __restrict__ Opart,
                                                     float* __restrict__ Lpart,
                                                     float* __restrict__ Mpart) {
    __shared__ u16 KQs[2 * 64 * 128];
    __shared__ u16 Vts[2 * 64 * 64];
    int id = blockIdx.x;
    int xcd = id & 7;
    int r = id >> 3;               // 0..127
    int g = xcd + 8 * (r & 3);     // (b*16+h) pinned per XCD
    int rem = r >> 2;              // 0..31
    int qt = rem & 15;
    int hx = rem >> 4;             // KV half: 0 or 1
    int b = g >> 4, h = g & 15;
    int n0 = qt * 128;
    int kv0 = hx * 1024;           // KV row base for this half
    int t = threadIdx.x, lane = t & 63, w = t >> 6;
    int lr = lane & 15, lg = lane >> 4;
    const char* QQg = (const char*)(QQ + ((size_t)(b * NH + h) * NN) * 128);
    const char* KKg = (const char*)(KK + ((size_t)(b * NH + h) * NN) * 128) + (size_t)kv0 * 256;
    const char* Vtg = (const char*)(Vt + ((size_t)(b * NH + h) * 64) * NN) + (size_t)kv0 * 2;

    short8 vones;
#pragma unroll
    for (int i = 0; i < 8; i++) vones[i] = (short)0x3F80;

#pragma unroll
    for (int i = 0; i < 4; i++)
        gload16(QQg + (size_t)n0 * 256 + i * 8192 + w * 1024 + lane * 16,
                (char*)KQs + i * 8192 + w * 1024);
    __syncthreads();
    short8 aq[4];
    {
        int row = w * 16 + lr;
#pragma unroll
        for (int ks = 0; ks < 4; ks++)
            aq[ks] = *reinterpret_cast<const short8*>(
                KQs + row * 128 + (((ks * 4 + lg) ^ (row & 7)) << 3));
    }
    __syncthreads();

#pragma unroll
    for (int i = 0; i < 2; i++)
        gload16(KKg + i * 8192 + w * 1024 + lane * 16, (char*)KQs + i * 8192 + w * 1024);
    gload16(Vtg + (size_t)(w * 8 + (lane >> 3)) * (NN * 2) + (lane & 7) * 16,
            (char*)Vts + w * 1024);
    __syncthreads();

    f32x4 O[4] = {};
    f32x4 O5 = {};
    float mrun = -1e30f;

    int cur = 0;
    for (int tt = 0; tt < 16; tt++) {
        if (tt < 15) {
            int m1 = (tt + 1) * 64;
            int nb = cur ^ 1;
#pragma unroll
            for (int i = 0; i < 2; i++)
                gload16(KKg + (size_t)m1 * 256 + i * 8192 + w * 1024 + lane * 16,
                        (char*)KQs + nb * 16384 + i * 8192 + w * 1024);
            gload16(Vtg + (size_t)(w * 8 + (lane >> 3)) * (NN * 2) + (size_t)m1 * 2 + (lane & 7) * 16,
                    (char*)Vts + nb * 8192 + w * 1024);
        }
        const u16* Kc = KQs + cur * 8192;
        const u16* Vc = Vts + cur * 4096;
        f32x4 S[4];
        __builtin_amdgcn_s_setprio(1);
#pragma unroll
        for (int ct = 0; ct < 4; ct++) {
            f32x4 s = {};
#pragma unroll
            for (int ks = 0; ks < 4; ks++) {
                int row = ct * 16 + lr;
                short8 bk = *reinterpret_cast<const short8*>(
                    Kc + row * 128 + (((ks * 4 + lg) ^ (row & 7)) << 3));
                s = __builtin_amdgcn_mfma_f32_16x16x32_bf16(bk, aq[ks], s, 0, 0, 0);
            }
            S[ct] = s;
        }
        __builtin_amdgcn_s_setprio(0);

        float mx = fmaxf(fmaxf(fmaxf(S[0][0], S[0][1]), fmaxf(S[0][2], S[0][3])),
                         fmaxf(fmaxf(S[1][0], S[1][1]), fmaxf(S[1][2], S[1][3])));
        mx = fmaxf(mx, fmaxf(fmaxf(fmaxf(S[2][0], S[2][1]), fmaxf(S[2][2], S[2][3])),
                             fmaxf(fmaxf(S[3][0], S[3][1]), fmaxf(S[3][2], S[3][3]))));
        mx = fmaxf(mx, __shfl_xor(mx, 16));
        mx = fmaxf(mx, __shfl_xor(mx, 32));
        if (__any(mx > mrun + 8.f)) {
            float newm = fmaxf(mrun, mx);
            float sf = exp2f(mrun - newm);
            mrun = newm;
            float sfq[4];
#pragma unroll
            for (int rg = 0; rg < 4; rg++)
                sfq[rg] = __shfl(sf, 4 * lg + rg);
#pragma unroll
            for (int rg = 0; rg < 4; rg++) {
                float s4 = sfq[rg];
#pragma unroll
                for (int dt = 0; dt < 4; dt++) O[dt][rg] *= s4;
                O5[rg] *= s4;
            }
        }
        // P = exp2(S - mrun) packed to bf16 pairs via v_cvt_pk_bf16_f32
        u32 dA[4], dB[4];
#pragma unroll
        for (int ct = 0; ct < 4; ct++) {
            float e0 = exp2f(S[ct][0] - mrun);
            float e1 = exp2f(S[ct][1] - mrun);
            float e2 = exp2f(S[ct][2] - mrun);
            float e3 = exp2f(S[ct][3] - mrun);
            dA[ct] = cvtpk_bf16(e0, e1);
            dB[ct] = cvtpk_bf16(e2, e3);
        }
        int lgh = lg >> 1;
        short8 pa[2];
#pragma unroll
        for (int ks = 0; ks < 2; ks++) {
            u32 selfA = lgh ? dA[2 * ks + 1] : dA[2 * ks];
            u32 selfB = lgh ? dB[2 * ks + 1] : dB[2 * ks];
            u32 crossA = lgh ? dA[2 * ks] : dA[2 * ks + 1];
            u32 crossB = lgh ? dB[2 * ks] : dB[2 * ks + 1];
            u32 FA = (u32)__shfl_xor((int)selfA, 16);
            u32 FB = (u32)__shfl_xor((int)selfB, 16);
            u32 EA = (u32)__shfl_xor((int)crossA, 32);
            u32 EB = (u32)__shfl_xor((int)crossB, 32);
            u32 GA = (u32)__shfl_xor((int)EA, 16);
            u32 GB = (u32)__shfl_xor((int)EB, 16);
            u32 XA = (lg == 0) ? selfA : (lg == 1) ? GA : (lg == 2) ? EA : FA;
            u32 XB = (lg == 0) ? selfB : (lg == 1) ? GB : (lg == 2) ? EB : FB;
            u32 YA = (lg == 0) ? FA : (lg == 1) ? EA : (lg == 2) ? GA : selfA;
            u32 YB = (lg == 0) ? FB : (lg == 1) ? EB : (lg == 2) ? GB : selfB;
            u32x4 pv; pv[0] = XA; pv[1] = XB; pv[2] = YA; pv[3] = YB;
            pa[ks] = __builtin_bit_cast(short8, pv);
        }
        __builtin_amdgcn_s_setprio(1);
#pragma unroll
        for (int dt = 0; dt < 4; dt++) {
#pragma unroll
            for (int ks = 0; ks < 2; ks++) {
                int vrow = dt * 16 + lr;
                short8 vf = *reinterpret_cast<const short8*>(
                    Vc + vrow * 64 + (((ks * 4 + lg) ^ (vrow & 7)) << 3));
                O[dt] = __builtin_amdgcn_mfma_f32_16x16x32_bf16(pa[ks], vf, O[dt], 0, 0, 0);
            }
        }
#pragma unroll
        for (int ks = 0; ks < 2; ks++)
            O5 = __builtin_amdgcn_mfma_f32_16x16x32_bf16(pa[ks], vones, O5, 0, 0, 0);
        __builtin_amdgcn_s_setprio(0);
        __syncthreads();
        cur ^= 1;
    }
    // epilogue: write unnormalized partials O, and per-row (m, l)
    float* Ob = Opart + (size_t)hx * 4194304 + ((size_t)g * NN) * 64;
    float mq[4];
#pragma unroll
    for (int rg = 0; rg < 4; rg++) mq[rg] = __shfl(mrun, 4 * lg + rg);
#pragma unroll
    for (int rg = 0; rg < 4; rg++) {
        int row = n0 + w * 16 + lg * 4 + rg;
#pragma unroll
        for (int dt = 0; dt < 4; dt++)
            Ob[(size_t)row * 64 + dt * 16 + lr] = O[dt][rg];
        if (lr == 0) {
            Lpart[hx * 65536 + g * NN + row] = O5[rg];
            Mpart[hx * 65536 + g * NN + row] = mq[rg];
        }
    }
}

// ---------------- combine: ctx = (O0*w0 + O1*w1)/(l0*w0 + l1*w1), wi = 2^(mi-max) ----------------
__global__ __launch_bounds__(256) void flash_combine(const float* __restrict__ Opart,
                                                     const float* __restrict__ Lpart,
                                                     const float* __restrict__ Mpart,
                                                     u16* __restrict__ ctx) {
    int idx = blockIdx.x * 256 + threadIdx.x;   // < 1048576
    int row = idx >> 4;                          // g*2048 + n  (0..65535)
    int dq = (idx & 15) * 4;
    float4 o0 = *reinterpret_cast<const float4*>(Opart + (size_t)row * 64 + dq);
    float4 o1 = *reinterpret_cast<const float4*>(Opart + 4194304 + (size_t)row * 64 + dq);
    float m0 = Mpart[row], m1 = Mpart[65536 + row];
    float l0 = Lpart[row], l1 = Lpart[65536 + row];
    float mf = fmaxf(m0, m1);
    float w0 = exp2f(m0 - mf), w1 = exp2f(m1 - mf);
    float rden = 1.0f / (l0 * w0 + l1 * w1);
    int g = row >> 11, n = row & 2047;
    int b = g >> 4, h = g & 15;
    us4 o;
    o[0] = f2bf((o0.x * w0 + o1.x * w1) * rden);
    o[1] = f2bf((o0.y * w0 + o1.y * w1) * rden);
    o[2] = f2bf((o0.z * w0 + o1.z * w1) * rden);
    o[3] = f2bf((o0.w * w0 + o1.w * w1) * rden);
    *reinterpret_cast<us4*>(ctx + ((size_t)(b * NN) + n) * 1024 + h * 64 + dq) = o;
}

extern "C" void kernel_launch(void* const* d_in, const int* in_sizes, int n_in,
                              void* d_out, int out_size, void* d_ws, size_t ws_size,
                              hipStream_t stream) {
    const float* x   = (const float*)d_in[0];
    const float* pos = (const float*)d_in[2];
    const float* Wq  = (const float*)d_in[3];
    const float* bq  = (const float*)d_in[4];
    const float* Wk  = (const float*)d_in[5];
    const float* bk  = (const float*)d_in[6];
    const float* Wv  = (const float*)d_in[7];
    const float* bv  = (const float*)d_in[8];
    const float* Wo  = (const float*)d_in[9];
    const float* bo  = (const float*)d_in[10];
    const float* qlw = (const float*)d_in[11];
    const float* qlb = (const float*)d_in[12];
    const float* klw = (const float*)d_in[13];
    const float* klb = (const float*)d_in[14];
    const float* Wp  = (const float*)d_in[15];
    const float* pbu = (const float*)d_in[16];
    const float* pbv = (const float*)d_in[17];
    float* out = (float*)d_out;

    char* ws = (char*)d_ws;
    u16*   xbf   = (u16*)(ws);                      //  8388608 B
    u16*   posbf = (u16*)(ws + 8388608);            //  8388608 B
    u16*   Wbf   = (u16*)(ws + 16777216);           //  5 x 2097152 B (q,k,v,p,o)
    u16*   pre   = (u16*)(ws + 27262976);           //  4 x 8388608 B bf16 (q,k,v,p)
    float* Opart = (float*)(ws + 27262976);         //  2 x 16777216 B (aliases pre, dead by flash)
    float* Lpart = (float*)(ws + 60817408);         //  524288 B
    float* Mpart = (float*)(ws + 61341696);         //  524288 B
    u16*   QQ    = (u16*)(ws + 94371840);           // 16777216 B
    u16*   KK    = (u16*)(ws + 111149056);          // 16777216 B
    u16*   Vt    = (u16*)(ws + 127926272);          //  8388608 B
    u16*   ctx   = (u16*)(ws + 136314880);          //  8388608 B  (total 144703488)

    cast_xpos<<<dim3(4096, 2), 256, 0, stream>>>(x, pos, xbf, posbf);
    cast_w<<<dim3(1024, 5), 256, 0, stream>>>(Wq, Wk, Wv, Wp, Wo, Wbf);

    proj_gemm<<<dim3(8, 32, 4), 256, 0, stream>>>(xbf, posbf, Wbf, pre, bq, bk, bv);
    post_fused<<<dim3(1024, 3), 256, 0, stream>>>(pre, qlw, qlb, klw, klb, pbu, pbv, QQ, KK, Vt);
    flash_attn<<<1024, 512, 0, stream>>>(QQ, KK, Vt, Opart, Lpart, Mpart);
    flash_combine<<<4096, 256, 0, stream>>>(Opart, Lpart, Mpart, ctx);
    out_gemm<<<dim3(8, 32), 256, 0, stream>>>(ctx, Wbf + 4 * 1048576, out, bo);
}

// Round 15
// 219.725 us; speedup vs baseline: 1.0158x; 1.0158x over previous
//
#include <hip/hip_runtime.h>
#include <stdint.h>

// WhaleAttention: B=2 N=2048 C=1024 H=16 D=64
// R15: revert split-K flash (R13 body = measured best 119us). proj_gemm epilogue
// writes V directly into Vt layout and P directly into KK[:,64:128] (no LN needed)
// -> deletes 32MB of pre/post traffic + shrinks post launch to LN-only.

typedef short short8 __attribute__((ext_vector_type(8)));
typedef float f32x4 __attribute__((ext_vector_type(4)));
typedef unsigned short us4 __attribute__((ext_vector_type(4)));
typedef unsigned int u32x4 __attribute__((ext_vector_type(4)));
typedef unsigned short u16;
typedef unsigned int u32;

#define NB 2
#define NN 2048
#define NC 1024
#define NH 16
#define ND 64

__device__ __forceinline__ u16 f2bf(float f) {
    unsigned int u = __float_as_uint(f);
    u += 0x7fffu + ((u >> 16) & 1u);
    return (u16)(u >> 16);
}
__device__ __forceinline__ float bf2f(u16 v) {
    return __uint_as_float(((u32)v) << 16);
}

__device__ __forceinline__ int swzc(int row, int c) {
    return (((c >> 3) ^ (row & 7)) << 3) | (c & 7);
}

__device__ __forceinline__ void gload16(const void* g, void* l) {
    __builtin_amdgcn_global_load_lds(
        (const __attribute__((address_space(1))) unsigned int*)g,
        (__attribute__((address_space(3))) unsigned int*)l, 16, 0, 0);
}

// ---------------- casts (merged) ----------------
__global__ __launch_bounds__(256) void cast_xpos(const float* __restrict__ x,
                                                 const float* __restrict__ pos,
                                                 u16* __restrict__ dx,
                                                 u16* __restrict__ dpos) {
    const float* s = blockIdx.y ? pos : x;
    u16* d = blockIdx.y ? dpos : dx;
    int i = blockIdx.x * 256 + threadIdx.x;
    float4 f = reinterpret_cast<const float4*>(s)[i];
    us4 o;
    o[0] = f2bf(f.x); o[1] = f2bf(f.y); o[2] = f2bf(f.z); o[3] = f2bf(f.w);
    reinterpret_cast<us4*>(d)[i] = o;
}

__global__ __launch_bounds__(256) void cast_w(const float* __restrict__ w0,
                                              const float* __restrict__ w1,
                                              const float* __restrict__ w2,
                                              const float* __restrict__ w3,
                                              const float* __restrict__ w4,
                                              u16* __restrict__ dst) {
    int z = blockIdx.y;
    const float* s = (z == 0) ? w0 : (z == 1) ? w1 : (z == 2) ? w2 : (z == 3) ? w3 : w4;
    u16* d = dst + (size_t)z * 1048576;
    int i = blockIdx.x * 256 + threadIdx.x;
    float4 f = reinterpret_cast<const float4*>(s)[i];
    us4 o;
    o[0] = f2bf(f.x); o[1] = f2bf(f.y); o[2] = f2bf(f.z); o[3] = f2bf(f.w);
    reinterpret_cast<us4*>(d)[i] = o;
}

// ---------------- GEMM C = A @ W^T (+bias); gload_lds + dbuf ----------------
// epilogue mode: 0 = fp32 out; 1 = bf16 row-major; 2 = Vt direct; 3 = KK[:,64:128] direct
__device__ __forceinline__ void gemm_stage(const u16* __restrict__ A,
                                           const u16* __restrict__ W,
                                           u16* As, u16* Bs,
                                           int m0, int n0, int kk, int w, int lane) {
    int lr4 = lane >> 2, lc8 = (lane & 3) * 8;
#pragma unroll
    for (int i = 0; i < 2; i++) {
        int rbase = w * 32 + i * 16;
        gload16(A + (size_t)(m0 + rbase + lr4) * 1024 + kk + lc8, As + rbase * 32);
        gload16(W + (size_t)(n0 + rbase + lr4) * 1024 + kk + lc8, Bs + rbase * 32);
    }
}

__device__ __forceinline__ void gemm_bt_body(const u16* __restrict__ A,
                                             const u16* __restrict__ W,
                                             float* __restrict__ outF,
                                             u16* __restrict__ outB,
                                             const float* __restrict__ bias,
                                             int m0, int n0, int mode) {
    __shared__ u16 As[2][128 * 32];
    __shared__ u16 Bs[2][128 * 32];
    int t = threadIdx.x, lane = t & 63, w = t >> 6;
    int wm = (w >> 1) * 64, wn = (w & 1) * 64;
    int lr = lane & 15, lg = lane >> 4;
    f32x4 acc[4][4] = {};

    gemm_stage(A, W, As[0], Bs[0], m0, n0, 0, w, lane);
    __syncthreads();
    int cur = 0;
    for (int kt = 0; kt < 32; kt++) {
        if (kt < 31)
            gemm_stage(A, W, As[cur ^ 1], Bs[cur ^ 1], m0, n0, (kt + 1) * 32, w, lane);
        const u16* Ac = As[cur];
        const u16* Bc = Bs[cur];
        short8 af[4], bw[4];
#pragma unroll
        for (int mt = 0; mt < 4; mt++)
            af[mt] = *reinterpret_cast<const short8*>(Ac + (wm + mt * 16 + lr) * 32 + lg * 8);
#pragma unroll
        for (int nt = 0; nt < 4; nt++)
            bw[nt] = *reinterpret_cast<const short8*>(Bc + (wn + nt * 16 + lr) * 32 + lg * 8);
#pragma unroll
        for (int mt = 0; mt < 4; mt++)
#pragma unroll
            for (int nt = 0; nt < 4; nt++)
                acc[mt][nt] = __builtin_amdgcn_mfma_f32_16x16x32_bf16(af[mt], bw[nt], acc[mt][nt], 0, 0, 0);
        __syncthreads();
        cur ^= 1;
    }
#pragma unroll
    for (int mt = 0; mt < 4; mt++) {
#pragma unroll
        for (int nt = 0; nt < 4; nt++) {
            int c = n0 + wn + nt * 16 + lr;
            float badd = bias ? bias[c] : 0.0f;
            int r = m0 + wm + mt * 16 + lg * 4;
#pragma unroll
            for (int rg = 0; rg < 4; rg++) {
                float val = acc[mt][nt][rg] + badd;
                int r2 = r + rg;
                if (mode == 0) {
                    outF[(size_t)r2 * 1024 + c] = val;
                } else if (mode == 1) {
                    outB[(size_t)r2 * 1024 + c] = f2bf(val);
                } else {
                    int b = r2 >> 11, n = r2 & 2047;
                    int h = c >> 6, d = c & 63;
                    u16 vb = f2bf(val);
                    if (mode == 2) {
                        int nsw = (n & ~63) | ((((n >> 3) & 7) ^ (d & 7)) << 3) | (n & 7);
                        outB[((size_t)(b * NH + h)) * 64 * NN + (size_t)d * NN + nsw] = vb;
                    } else {
                        outB[((size_t)(b * NH + h) * NN + n) * 128 + swzc(n, 64 + d)] = vb;
                    }
                }
            }
        }
    }
}

// z=0:q(bq)->pre0 1:k(bk)->pre1 2:v(bv)->Vt direct 3:p->KK[:,64:128] direct
__global__ __launch_bounds__(256) void proj_gemm(const u16* __restrict__ xbf,
                                                 const u16* __restrict__ posbf,
                                                 const u16* __restrict__ Wbase,
                                                 u16* __restrict__ prebase,
                                                 u16* __restrict__ Vt,
                                                 u16* __restrict__ KK,
                                                 const float* __restrict__ bq,
                                                 const float* __restrict__ bk,
                                                 const float* __restrict__ bv) {
    int z = blockIdx.z;
    const u16* A = (z == 3) ? posbf : xbf;
    const u16* W = Wbase + (size_t)z * 1048576;
    u16* outB = (z == 0) ? prebase : (z == 1) ? (prebase + 4194304) : (z == 2) ? Vt : KK;
    const float* bias = (z == 0) ? bq : ((z == 1) ? bk : ((z == 2) ? bv : (const float*)nullptr));
    int mode = (z <= 1) ? 1 : ((z == 2) ? 2 : 3);
    gemm_bt_body(A, W, nullptr, outB, bias, blockIdx.y * 128, blockIdx.x * 128, mode);
}

__global__ __launch_bounds__(256) void out_gemm(const u16* __restrict__ ctx,
                                                const u16* __restrict__ Wo,
                                                float* __restrict__ out,
                                                const float* __restrict__ bo) {
    gemm_bt_body(ctx, Wo, out, nullptr, bo, blockIdx.y * 128, blockIdx.x * 128, 0);
}

// ---------------- LN on bf16 q/k rows; QQ=[s*(q^+u)|s*(q^+v)], KK[:,0:64]=k^ (pre-swizzled) ----------------
__global__ __launch_bounds__(256) void post_qk(const u16* __restrict__ prebase,
                                               const float* __restrict__ qw, const float* __restrict__ qb,
                                               const float* __restrict__ kw, const float* __restrict__ kb,
                                               const float* __restrict__ pbu, const float* __restrict__ pbv,
                                               u16* __restrict__ QQ, u16* __restrict__ KK) {
    const float QSC = 0.125f * 1.44269504089f;
    int isq = (blockIdx.y == 0);
    const u16* pre = prebase + (isq ? 0 : (size_t)4194304);
    const float* lw = isq ? qw : kw;
    const float* lb = isq ? qb : kb;
    int wv = threadIdx.x >> 6, lane = threadIdx.x & 63;
    int row = blockIdx.x * 4 + wv;   // 0..4095
    int b = row >> 11, n = row & 2047;
    const u16* pr = pre + (size_t)row * 1024;
    float vals[16];
    float s = 0.f, s2 = 0.f;
#pragma unroll
    for (int i = 0; i < 2; i++) {
        short8 v8 = *reinterpret_cast<const short8*>(pr + i * 512 + lane * 8);
#pragma unroll
        for (int j = 0; j < 8; j++) {
            float f = bf2f((u16)v8[j]);
            vals[i * 8 + j] = f;
            s += f; s2 += f * f;
        }
    }
#pragma unroll
    for (int m = 1; m < 64; m <<= 1) { s += __shfl_xor(s, m); s2 += __shfl_xor(s2, m); }
    float mean = s * (1.f / 1024.f);
    float var = s2 * (1.f / 1024.f) - mean * mean;
    float inv = rsqrtf(var + 1e-6f);
#pragma unroll
    for (int i = 0; i < 2; i++) {
        int c0 = i * 512 + lane * 8;
        int h = c0 >> 6, d0 = c0 & 63;
        size_t base = ((size_t)(b * NH + h) * NN + n) * 128;
        if (isq) {
            short8 o0, o1;
#pragma unroll
            for (int j = 0; j < 8; j++) {
                float xn = (vals[i * 8 + j] - mean) * inv * lw[c0 + j] + lb[c0 + j];
                o0[j] = (short)f2bf((xn + pbu[h * 64 + d0 + j]) * QSC);
                o1[j] = (short)f2bf((xn + pbv[h * 64 + d0 + j]) * QSC);
            }
            *reinterpret_cast<short8*>(QQ + base + swzc(n, d0)) = o0;
            *reinterpret_cast<short8*>(QQ + base + swzc(n, d0 + 64)) = o1;
        } else {
            short8 o0;
#pragma unroll
            for (int j = 0; j < 8; j++) {
                float xn = (vals[i * 8 + j] - mean) * inv * lw[c0 + j] + lb[c0 + j];
                o0[j] = (short)f2bf(xn);
            }
            *reinterpret_cast<short8*>(KK + base + swzc(n, d0)) = o0;
        }
    }
}

// ---------------- flash attention (R13/R11 best): 8 waves x 16 q-rows, KVBLK=64,
//                  K/V dbuf issue-early, swapped QK^T + in-reg P, XCD swizzle ----------------
__global__ __launch_bounds__(512, 4) void flash_attn(const u16* __restrict__ QQ,
                                                     const u16* __restrict__ KK,
                                                     const u16* __restrict__ Vt,
                                                     u16* __restrict__ ctx) {
    __shared__ u16 KQs[2 * 64 * 128];
    __shared__ u16 Vts[2 * 64 * 64];
    int id = blockIdx.x;
    int xcd = id & 7;
    int s5 = id >> 3;
    int g = xcd + 8 * (s5 & 3);    // (b*16+h) pinned per XCD
    int qt = s5 >> 2;
    int b = g >> 4, h = g & 15;
    int n0 = qt * 128;
    int t = threadIdx.x, lane = t & 63, w = t >> 6;
    int lr = lane & 15, lg = lane >> 4;
    const char* QQg = (const char*)(QQ + ((size_t)(b * NH + h) * NN) * 128);
    const char* KKg = (const char*)(KK + ((size_t)(b * NH + h) * NN) * 128);
    const char* Vtg = (const char*)(Vt + ((size_t)(b * NH + h) * 64) * NN);

    short8 vones;
#pragma unroll
    for (int i = 0; i < 8; i++) vones[i] = (short)0x3F80;

#pragma unroll
    for (int i = 0; i < 4; i++)
        gload16(QQg + (size_t)n0 * 256 + i * 8192 + w * 1024 + lane * 16,
                (char*)KQs + i * 8192 + w * 1024);
    __syncthreads();
    short8 aq[4];
    {
        int row = w * 16 + lr;
#pragma unroll
        for (int ks = 0; ks < 4; ks++)
            aq[ks] = *reinterpret_cast<const short8*>(
                KQs + row * 128 + (((ks * 4 + lg) ^ (row & 7)) << 3));
    }
    __syncthreads();

#pragma unroll
    for (int i = 0; i < 2; i++)
        gload16(KKg + i * 8192 + w * 1024 + lane * 16, (char*)KQs + i * 8192 + w * 1024);
    gload16(Vtg + (size_t)(w * 8 + (lane >> 3)) * (NN * 2) + (lane & 7) * 16,
            (char*)Vts + w * 1024);
    __syncthreads();

    f32x4 O[4] = {};
    f32x4 O5 = {};
    float mrun = -1e30f;

    int cur = 0;
    for (int tt = 0; tt < 32; tt++) {
        if (tt < 31) {
            int m1 = (tt + 1) * 64;
            int nb = cur ^ 1;
#pragma unroll
            for (int i = 0; i < 2; i++)
                gload16(KKg + (size_t)m1 * 256 + i * 8192 + w * 1024 + lane * 16,
                        (char*)KQs + nb * 16384 + i * 8192 + w * 1024);
            gload16(Vtg + (size_t)(w * 8 + (lane >> 3)) * (NN * 2) + (size_t)m1 * 2 + (lane & 7) * 16,
                    (char*)Vts + nb * 8192 + w * 1024);
        }
        const u16* Kc = KQs + cur * 8192;
        const u16* Vc = Vts + cur * 4096;
        f32x4 S[4];
        __builtin_amdgcn_s_setprio(1);
#pragma unroll
        for (int ct = 0; ct < 4; ct++) {
            f32x4 s = {};
#pragma unroll
            for (int ks = 0; ks < 4; ks++) {
                int row = ct * 16 + lr;
                short8 bk = *reinterpret_cast<const short8*>(
                    Kc + row * 128 + (((ks * 4 + lg) ^ (row & 7)) << 3));
                s = __builtin_amdgcn_mfma_f32_16x16x32_bf16(bk, aq[ks], s, 0, 0, 0);
            }
            S[ct] = s;
        }
        __builtin_amdgcn_s_setprio(0);

        float mx = fmaxf(fmaxf(fmaxf(S[0][0], S[0][1]), fmaxf(S[0][2], S[0][3])),
                         fmaxf(fmaxf(S[1][0], S[1][1]), fmaxf(S[1][2], S[1][3])));
        mx = fmaxf(mx, fmaxf(fmaxf(fmaxf(S[2][0], S[2][1]), fmaxf(S[2][2], S[2][3])),
                             fmaxf(fmaxf(S[3][0], S[3][1]), fmaxf(S[3][2], S[3][3]))));
        mx = fmaxf(mx, __shfl_xor(mx, 16));
        mx = fmaxf(mx, __shfl_xor(mx, 32));
        if (__any(mx > mrun + 8.f)) {
            float newm = fmaxf(mrun, mx);
            float sf = exp2f(mrun - newm);
            mrun = newm;
            float sfq[4];
#pragma unroll
            for (int rg = 0; rg < 4; rg++)
                sfq[rg] = __shfl(sf, 4 * lg + rg);
#pragma unroll
            for (int rg = 0; rg < 4; rg++) {
                float s4 = sfq[rg];
#pragma unroll
                for (int dt = 0; dt < 4; dt++) O[dt][rg] *= s4;
                O5[rg] *= s4;
            }
        }
        u32 dA[4], dB[4];
#pragma unroll
        for (int ct = 0; ct < 4; ct++) {
            u16 b0 = f2bf(exp2f(S[ct][0] - mrun));
            u16 b1 = f2bf(exp2f(S[ct][1] - mrun));
            u16 b2 = f2bf(exp2f(S[ct][2] - mrun));
            u16 b3 = f2bf(exp2f(S[ct][3] - mrun));
            dA[ct] = (u32)b0 | ((u32)b1 << 16);
            dB[ct] = (u32)b2 | ((u32)b3 << 16);
        }
        int lgh = lg >> 1;
        short8 pa[2];
#pragma unroll
        for (int ks = 0; ks < 2; ks++) {
            u32 selfA = lgh ? dA[2 * ks + 1] : dA[2 * ks];
            u32 selfB = lgh ? dB[2 * ks + 1] : dB[2 * ks];
            u32 crossA = lgh ? dA[2 * ks] : dA[2 * ks + 1];
            u32 crossB = lgh ? dB[2 * ks] : dB[2 * ks + 1];
            u32 FA = (u32)__shfl_xor((int)selfA, 16);
            u32 FB = (u32)__shfl_xor((int)selfB, 16);
            u32 EA = (u32)__shfl_xor((int)crossA, 32);
            u32 EB = (u32)__shfl_xor((int)crossB, 32);
            u32 GA = (u32)__shfl_xor((int)EA, 16);
            u32 GB = (u32)__shfl_xor((int)EB, 16);
            u32 XA = (lg == 0) ? selfA : (lg == 1) ? GA : (lg == 2) ? EA : FA;
            u32 XB = (lg == 0) ? selfB : (lg == 1) ? GB : (lg == 2) ? EB : FB;
            u32 YA = (lg == 0) ? FA : (lg == 1) ? EA : (lg == 2) ? GA : selfA;
            u32 YB = (lg == 0) ? FB : (lg == 1) ? EB : (lg == 2) ? GB : selfB;
            u32x4 pv; pv[0] = XA; pv[1] = XB; pv[2] = YA; pv[3] = YB;
            pa[ks] = __builtin_bit_cast(short8, pv);
        }
        __builtin_amdgcn_s_setprio(1);
#pragma unroll
        for (int dt = 0; dt < 4; dt++) {
#pragma unroll
            for (int ks = 0; ks < 2; ks++) {
                int vrow = dt * 16 + lr;
                short8 vf = *reinterpret_cast<const short8*>(
                    Vc + vrow * 64 + (((ks * 4 + lg) ^ (vrow & 7)) << 3));
                O[dt] = __builtin_amdgcn_mfma_f32_16x16x32_bf16(pa[ks], vf, O[dt], 0, 0, 0);
            }
        }
#pragma unroll
        for (int ks = 0; ks < 2; ks++)
            O5 = __builtin_amdgcn_mfma_f32_16x16x32_bf16(pa[ks], vones, O5, 0, 0, 0);
        __builtin_amdgcn_s_setprio(0);
        __syncthreads();
        cur ^= 1;
    }
#pragma unroll
    for (int dt = 0; dt < 4; dt++) {
#pragma unroll
        for (int rg = 0; rg < 4; rg++) {
            int n = n0 + w * 16 + lg * 4 + rg;
            float oo = O[dt][rg] / O5[rg];
            ctx[((size_t)(b * NN) + n) * 1024 + h * 64 + dt * 16 + lr] = f2bf(oo);
        }
    }
}

extern "C" void kernel_launch(void* const* d_in, const int* in_sizes, int n_in,
                              void* d_out, int out_size, void* d_ws, size_t ws_size,
                              hipStream_t stream) {
    const float* x   = (const float*)d_in[0];
    const float* pos = (const float*)d_in[2];
    const float* Wq  = (const float*)d_in[3];
    const float* bq  = (const float*)d_in[4];
    const float* Wk  = (const float*)d_in[5];
    const float* bk  = (const float*)d_in[6];
    const float* Wv  = (const float*)d_in[7];
    const float* bv  = (const float*)d_in[8];
    const float* Wo  = (const float*)d_in[9];
    const float* bo  = (const float*)d_in[10];
    const float* qlw = (const float*)d_in[11];
    const float* qlb = (const float*)d_in[12];
    const float* klw = (const float*)d_in[13];
    const float* klb = (const float*)d_in[14];
    const float* Wp  = (const float*)d_in[15];
    const float* pbu = (const float*)d_in[16];
    const float* pbv = (const float*)d_in[17];
    float* out = (float*)d_out;

    char* ws = (char*)d_ws;
    u16*   xbf   = (u16*)(ws);                      //  8388608 B
    u16*   posbf = (u16*)(ws + 8388608);            //  8388608 B
    u16*   Wbf   = (u16*)(ws + 16777216);           //  5 x 2097152 B (q,k,v,p,o)
    u16*   pre   = (u16*)(ws + 27262976);           //  2 x 8388608 B bf16 (q,k)
    u16*   QQ    = (u16*)(ws + 94371840);           // 16777216 B
    u16*   KK    = (u16*)(ws + 111149056);          // 16777216 B
    u16*   Vt    = (u16*)(ws + 127926272);          //  8388608 B
    u16*   ctx   = (u16*)(ws + 136314880);          //  8388608 B  (total 144703488)

    cast_xpos<<<dim3(4096, 2), 256, 0, stream>>>(x, pos, xbf, posbf);
    cast_w<<<dim3(1024, 5), 256, 0, stream>>>(Wq, Wk, Wv, Wp, Wo, Wbf);

    proj_gemm<<<dim3(8, 32, 4), 256, 0, stream>>>(xbf, posbf, Wbf, pre, Vt, KK, bq, bk, bv);
    post_qk<<<dim3(1024, 2), 256, 0, stream>>>(pre, qlw, qlb, klw, klb, pbu, pbv, QQ, KK);
    flash_attn<<<512, 512, 0, stream>>>(QQ, KK, Vt, ctx);
    out_gemm<<<dim3(8, 32), 256, 0, stream>>>(ctx, Wbf + 4 * 1048576, out, bo);
}

// Round 18
// 213.116 us; speedup vs baseline: 1.0474x; 1.0310x over previous
//
#include <hip/hip_runtime.h>
#include <stdint.h>

// WhaleAttention: B=2 N=2048 C=1024 H=16 D=64
// R18 = R15 (last passing, 219.7us) + v_cvt_pk_bf16_f32 P-pack only (proven in R14).
// permlane32_swap BANNED after 2 correctness failures (R16/R17) - all cross-lane
// traffic back to __shfl_xor as in R15.

typedef short short8 __attribute__((ext_vector_type(8)));
typedef float f32x4 __attribute__((ext_vector_type(4)));
typedef unsigned short us4 __attribute__((ext_vector_type(4)));
typedef unsigned int u32x4 __attribute__((ext_vector_type(4)));
typedef unsigned short u16;
typedef unsigned int u32;

#define NB 2
#define NN 2048
#define NC 1024
#define NH 16
#define ND 64

__device__ __forceinline__ u16 f2bf(float f) {
    unsigned int u = __float_as_uint(f);
    u += 0x7fffu + ((u >> 16) & 1u);
    return (u16)(u >> 16);
}
__device__ __forceinline__ float bf2f(u16 v) {
    return __uint_as_float(((u32)v) << 16);
}
__device__ __forceinline__ u32 cvtpk_bf16(float lo, float hi) {
    u32 d;
    asm("v_cvt_pk_bf16_f32 %0, %1, %2" : "=v"(d) : "v"(lo), "v"(hi));
    return d;
}

__device__ __forceinline__ int swzc(int row, int c) {
    return (((c >> 3) ^ (row & 7)) << 3) | (c & 7);
}

__device__ __forceinline__ void gload16(const void* g, void* l) {
    __builtin_amdgcn_global_load_lds(
        (const __attribute__((address_space(1))) unsigned int*)g,
        (__attribute__((address_space(3))) unsigned int*)l, 16, 0, 0);
}

// ---------------- casts (merged) ----------------
__global__ __launch_bounds__(256) void cast_xpos(const float* __restrict__ x,
                                                 const float* __restrict__ pos,
                                                 u16* __restrict__ dx,
                                                 u16* __restrict__ dpos) {
    const float* s = blockIdx.y ? pos : x;
    u16* d = blockIdx.y ? dpos : dx;
    int i = blockIdx.x * 256 + threadIdx.x;
    float4 f = reinterpret_cast<const float4*>(s)[i];
    us4 o;
    o[0] = f2bf(f.x); o[1] = f2bf(f.y); o[2] = f2bf(f.z); o[3] = f2bf(f.w);
    reinterpret_cast<us4*>(d)[i] = o;
}

__global__ __launch_bounds__(256) void cast_w(const float* __restrict__ w0,
                                              const float* __restrict__ w1,
                                              const float* __restrict__ w2,
                                              const float* __restrict__ w3,
                                              const float* __restrict__ w4,
                                              u16* __restrict__ dst) {
    int z = blockIdx.y;
    const float* s = (z == 0) ? w0 : (z == 1) ? w1 : (z == 2) ? w2 : (z == 3) ? w3 : w4;
    u16* d = dst + (size_t)z * 1048576;
    int i = blockIdx.x * 256 + threadIdx.x;
    float4 f = reinterpret_cast<const float4*>(s)[i];
    us4 o;
    o[0] = f2bf(f.x); o[1] = f2bf(f.y); o[2] = f2bf(f.z); o[3] = f2bf(f.w);
    reinterpret_cast<us4*>(d)[i] = o;
}

// ---------------- GEMM C = A @ W^T (+bias); gload_lds + dbuf ----------------
// epilogue mode: 0 = fp32 out; 1 = bf16 row-major; 2 = Vt direct; 3 = KK[:,64:128] direct
__device__ __forceinline__ void gemm_stage(const u16* __restrict__ A,
                                           const u16* __restrict__ W,
                                           u16* As, u16* Bs,
                                           int m0, int n0, int kk, int w, int lane) {
    int lr4 = lane >> 2, lc8 = (lane & 3) * 8;
#pragma unroll
    for (int i = 0; i < 2; i++) {
        int rbase = w * 32 + i * 16;
        gload16(A + (size_t)(m0 + rbase + lr4) * 1024 + kk + lc8, As + rbase * 32);
        gload16(W + (size_t)(n0 + rbase + lr4) * 1024 + kk + lc8, Bs + rbase * 32);
    }
}

__device__ __forceinline__ void gemm_bt_body(const u16* __restrict__ A,
                                             const u16* __restrict__ W,
                                             float* __restrict__ outF,
                                             u16* __restrict__ outB,
                                             const float* __restrict__ bias,
                                             int m0, int n0, int mode) {
    __shared__ u16 As[2][128 * 32];
    __shared__ u16 Bs[2][128 * 32];
    int t = threadIdx.x, lane = t & 63, w = t >> 6;
    int wm = (w >> 1) * 64, wn = (w & 1) * 64;
    int lr = lane & 15, lg = lane >> 4;
    f32x4 acc[4][4] = {};

    gemm_stage(A, W, As[0], Bs[0], m0, n0, 0, w, lane);
    __syncthreads();
    int cur = 0;
    for (int kt = 0; kt < 32; kt++) {
        if (kt < 31)
            gemm_stage(A, W, As[cur ^ 1], Bs[cur ^ 1], m0, n0, (kt + 1) * 32, w, lane);
        const u16* Ac = As[cur];
        const u16* Bc = Bs[cur];
        short8 af[4], bw[4];
#pragma unroll
        for (int mt = 0; mt < 4; mt++)
            af[mt] = *reinterpret_cast<const short8*>(Ac + (wm + mt * 16 + lr) * 32 + lg * 8);
#pragma unroll
        for (int nt = 0; nt < 4; nt++)
            bw[nt] = *reinterpret_cast<const short8*>(Bc + (wn + nt * 16 + lr) * 32 + lg * 8);
#pragma unroll
        for (int mt = 0; mt < 4; mt++)
#pragma unroll
            for (int nt = 0; nt < 4; nt++)
                acc[mt][nt] = __builtin_amdgcn_mfma_f32_16x16x32_bf16(af[mt], bw[nt], acc[mt][nt], 0, 0, 0);
        __syncthreads();
        cur ^= 1;
    }
#pragma unroll
    for (int mt = 0; mt < 4; mt++) {
#pragma unroll
        for (int nt = 0; nt < 4; nt++) {
            int c = n0 + wn + nt * 16 + lr;
            float badd = bias ? bias[c] : 0.0f;
            int r = m0 + wm + mt * 16 + lg * 4;
#pragma unroll
            for (int rg = 0; rg < 4; rg++) {
                float val = acc[mt][nt][rg] + badd;
                int r2 = r + rg;
                if (mode == 0) {
                    outF[(size_t)r2 * 1024 + c] = val;
                } else if (mode == 1) {
                    outB[(size_t)r2 * 1024 + c] = f2bf(val);
                } else {
                    int b = r2 >> 11, n = r2 & 2047;
                    int h = c >> 6, d = c & 63;
                    u16 vb = f2bf(val);
                    if (mode == 2) {
                        int nsw = (n & ~63) | ((((n >> 3) & 7) ^ (d & 7)) << 3) | (n & 7);
                        outB[((size_t)(b * NH + h)) * 64 * NN + (size_t)d * NN + nsw] = vb;
                    } else {
                        outB[((size_t)(b * NH + h) * NN + n) * 128 + swzc(n, 64 + d)] = vb;
                    }
                }
            }
        }
    }
}

// z=0:q(bq)->pre0 1:k(bk)->pre1 2:v(bv)->Vt direct 3:p->KK[:,64:128] direct
__global__ __launch_bounds__(256) void proj_gemm(const u16* __restrict__ xbf,
                                                 const u16* __restrict__ posbf,
                                                 const u16* __restrict__ Wbase,
                                                 u16* __restrict__ prebase,
                                                 u16* __restrict__ Vt,
                                                 u16* __restrict__ KK,
                                                 const float* __restrict__ bq,
                                                 const float* __restrict__ bk,
                                                 const float* __restrict__ bv) {
    int z = blockIdx.z;
    const u16* A = (z == 3) ? posbf : xbf;
    const u16* W = Wbase + (size_t)z * 1048576;
    u16* outB = (z == 0) ? prebase : (z == 1) ? (prebase + 4194304) : (z == 2) ? Vt : KK;
    const float* bias = (z == 0) ? bq : ((z == 1) ? bk : ((z == 2) ? bv : (const float*)nullptr));
    int mode = (z <= 1) ? 1 : ((z == 2) ? 2 : 3);
    gemm_bt_body(A, W, nullptr, outB, bias, blockIdx.y * 128, blockIdx.x * 128, mode);
}

__global__ __launch_bounds__(256) void out_gemm(const u16* __restrict__ ctx,
                                                const u16* __restrict__ Wo,
                                                float* __restrict__ out,
                                                const float* __restrict__ bo) {
    gemm_bt_body(ctx, Wo, out, nullptr, bo, blockIdx.y * 128, blockIdx.x * 128, 0);
}

// ---------------- LN on bf16 q/k rows; QQ=[s*(q^+u)|s*(q^+v)], KK[:,0:64]=k^ (pre-swizzled) ----------------
__global__ __launch_bounds__(256) void post_qk(const u16* __restrict__ prebase,
                                               const float* __restrict__ qw, const float* __restrict__ qb,
                                               const float* __restrict__ kw, const float* __restrict__ kb,
                                               const float* __restrict__ pbu, const float* __restrict__ pbv,
                                               u16* __restrict__ QQ, u16* __restrict__ KK) {
    const float QSC = 0.125f * 1.44269504089f;
    int isq = (blockIdx.y == 0);
    const u16* pre = prebase + (isq ? 0 : (size_t)4194304);
    const float* lw = isq ? qw : kw;
    const float* lb = isq ? qb : kb;
    int wv = threadIdx.x >> 6, lane = threadIdx.x & 63;
    int row = blockIdx.x * 4 + wv;   // 0..4095
    int b = row >> 11, n = row & 2047;
    const u16* pr = pre + (size_t)row * 1024;
    float vals[16];
    float s = 0.f, s2 = 0.f;
#pragma unroll
    for (int i = 0; i < 2; i++) {
        short8 v8 = *reinterpret_cast<const short8*>(pr + i * 512 + lane * 8);
#pragma unroll
        for (int j = 0; j < 8; j++) {
            float f = bf2f((u16)v8[j]);
            vals[i * 8 + j] = f;
            s += f; s2 += f * f;
        }
    }
#pragma unroll
    for (int m = 1; m < 64; m <<= 1) { s += __shfl_xor(s, m); s2 += __shfl_xor(s2, m); }
    float mean = s * (1.f / 1024.f);
    float var = s2 * (1.f / 1024.f) - mean * mean;
    float inv = rsqrtf(var + 1e-6f);
#pragma unroll
    for (int i = 0; i < 2; i++) {
        int c0 = i * 512 + lane * 8;
        int h = c0 >> 6, d0 = c0 & 63;
        size_t base = ((size_t)(b * NH + h) * NN + n) * 128;
        if (isq) {
            short8 o0, o1;
#pragma unroll
            for (int j = 0; j < 8; j++) {
                float xn = (vals[i * 8 + j] - mean) * inv * lw[c0 + j] + lb[c0 + j];
                o0[j] = (short)f2bf((xn + pbu[h * 64 + d0 + j]) * QSC);
                o1[j] = (short)f2bf((xn + pbv[h * 64 + d0 + j]) * QSC);
            }
            *reinterpret_cast<short8*>(QQ + base + swzc(n, d0)) = o0;
            *reinterpret_cast<short8*>(QQ + base + swzc(n, d0 + 64)) = o1;
        } else {
            short8 o0;
#pragma unroll
            for (int j = 0; j < 8; j++) {
                float xn = (vals[i * 8 + j] - mean) * inv * lw[c0 + j] + lb[c0 + j];
                o0[j] = (short)f2bf(xn);
            }
            *reinterpret_cast<short8*>(KK + base + swzc(n, d0)) = o0;
        }
    }
}

// ---------------- flash attention (R15 body + cvt_pk pack): 8 waves x 16 q-rows,
//                  KVBLK=64, K/V dbuf issue-early, swapped QK^T + in-reg P, XCD swizzle ----------------
__global__ __launch_bounds__(512, 4) void flash_attn(const u16* __restrict__ QQ,
                                                     const u16* __restrict__ KK,
                                                     const u16* __restrict__ Vt,
                                                     u16* __restrict__ ctx) {
    __shared__ u16 KQs[2 * 64 * 128];
    __shared__ u16 Vts[2 * 64 * 64];
    int id = blockIdx.x;
    int xcd = id & 7;
    int s5 = id >> 3;
    int g = xcd + 8 * (s5 & 3);    // (b*16+h) pinned per XCD
    int qt = s5 >> 2;
    int b = g >> 4, h = g & 15;
    int n0 = qt * 128;
    int t = threadIdx.x, lane = t & 63, w = t >> 6;
    int lr = lane & 15, lg = lane >> 4;
    const char* QQg = (const char*)(QQ + ((size_t)(b * NH + h) * NN) * 128);
    const char* KKg = (const char*)(KK + ((size_t)(b * NH + h) * NN) * 128);
    const char* Vtg = (const char*)(Vt + ((size_t)(b * NH + h) * 64) * NN);

    short8 vones;
#pragma unroll
    for (int i = 0; i < 8; i++) vones[i] = (short)0x3F80;

#pragma unroll
    for (int i = 0; i < 4; i++)
        gload16(QQg + (size_t)n0 * 256 + i * 8192 + w * 1024 + lane * 16,
                (char*)KQs + i * 8192 + w * 1024);
    __syncthreads();
    short8 aq[4];
    {
        int row = w * 16 + lr;
#pragma unroll
        for (int ks = 0; ks < 4; ks++)
            aq[ks] = *reinterpret_cast<const short8*>(
                KQs + row * 128 + (((ks * 4 + lg) ^ (row & 7)) << 3));
    }
    __syncthreads();

#pragma unroll
    for (int i = 0; i < 2; i++)
        gload16(KKg + i * 8192 + w * 1024 + lane * 16, (char*)KQs + i * 8192 + w * 1024);
    gload16(Vtg + (size_t)(w * 8 + (lane >> 3)) * (NN * 2) + (lane & 7) * 16,
            (char*)Vts + w * 1024);
    __syncthreads();

    f32x4 O[4] = {};
    f32x4 O5 = {};
    float mrun = -1e30f;

    int cur = 0;
    for (int tt = 0; tt < 32; tt++) {
        if (tt < 31) {
            int m1 = (tt + 1) * 64;
            int nb = cur ^ 1;
#pragma unroll
            for (int i = 0; i < 2; i++)
                gload16(KKg + (size_t)m1 * 256 + i * 8192 + w * 1024 + lane * 16,
                        (char*)KQs + nb * 16384 + i * 8192 + w * 1024);
            gload16(Vtg + (size_t)(w * 8 + (lane >> 3)) * (NN * 2) + (size_t)m1 * 2 + (lane & 7) * 16,
                    (char*)Vts + nb * 8192 + w * 1024);
        }
        const u16* Kc = KQs + cur * 8192;
        const u16* Vc = Vts + cur * 4096;
        f32x4 S[4];
        __builtin_amdgcn_s_setprio(1);
#pragma unroll
        for (int ct = 0; ct < 4; ct++) {
            f32x4 s = {};
#pragma unroll
            for (int ks = 0; ks < 4; ks++) {
                int row = ct * 16 + lr;
                short8 bk = *reinterpret_cast<const short8*>(
                    Kc + row * 128 + (((ks * 4 + lg) ^ (row & 7)) << 3));
                s = __builtin_amdgcn_mfma_f32_16x16x32_bf16(bk, aq[ks], s, 0, 0, 0);
            }
            S[ct] = s;
        }
        __builtin_amdgcn_s_setprio(0);

        float mx = fmaxf(fmaxf(fmaxf(S[0][0], S[0][1]), fmaxf(S[0][2], S[0][3])),
                         fmaxf(fmaxf(S[1][0], S[1][1]), fmaxf(S[1][2], S[1][3])));
        mx = fmaxf(mx, fmaxf(fmaxf(fmaxf(S[2][0], S[2][1]), fmaxf(S[2][2], S[2][3])),
                             fmaxf(fmaxf(S[3][0], S[3][1]), fmaxf(S[3][2], S[3][3]))));
        mx = fmaxf(mx, __shfl_xor(mx, 16));
        mx = fmaxf(mx, __shfl_xor(mx, 32));
        if (__any(mx > mrun + 8.f)) {
            float newm = fmaxf(mrun, mx);
            float sf = exp2f(mrun - newm);
            mrun = newm;
            float sfq[4];
#pragma unroll
            for (int rg = 0; rg < 4; rg++)
                sfq[rg] = __shfl(sf, 4 * lg + rg);
#pragma unroll
            for (int rg = 0; rg < 4; rg++) {
                float s4 = sfq[rg];
#pragma unroll
                for (int dt = 0; dt < 4; dt++) O[dt][rg] *= s4;
                O5[rg] *= s4;
            }
        }
        // P = exp2(S - mrun) packed via v_cvt_pk_bf16_f32 (RNE, proven in R14)
        u32 dA[4], dB[4];
#pragma unroll
        for (int ct = 0; ct < 4; ct++) {
            float e0 = exp2f(S[ct][0] - mrun);
            float e1 = exp2f(S[ct][1] - mrun);
            float e2 = exp2f(S[ct][2] - mrun);
            float e3 = exp2f(S[ct][3] - mrun);
            dA[ct] = cvtpk_bf16(e0, e1);
            dB[ct] = cvtpk_bf16(e2, e3);
        }
        int lgh = lg >> 1;
        short8 pa[2];
#pragma unroll
        for (int ks = 0; ks < 2; ks++) {
            u32 selfA = lgh ? dA[2 * ks + 1] : dA[2 * ks];
            u32 selfB = lgh ? dB[2 * ks + 1] : dB[2 * ks];
            u32 crossA = lgh ? dA[2 * ks] : dA[2 * ks + 1];
            u32 crossB = lgh ? dB[2 * ks] : dB[2 * ks + 1];
            u32 FA = (u32)__shfl_xor((int)selfA, 16);
            u32 FB = (u32)__shfl_xor((int)selfB, 16);
            u32 EA = (u32)__shfl_xor((int)crossA, 32);
            u32 EB = (u32)__shfl_xor((int)crossB, 32);
            u32 GA = (u32)__shfl_xor((int)EA, 16);
            u32 GB = (u32)__shfl_xor((int)EB, 16);
            u32 XA = (lg == 0) ? selfA : (lg == 1) ? GA : (lg == 2) ? EA : FA;
            u32 XB = (lg == 0) ? selfB : (lg == 1) ? GB : (lg == 2) ? EB : FB;
            u32 YA = (lg == 0) ? FA : (lg == 1) ? EA : (lg == 2) ? GA : selfA;
            u32 YB = (lg == 0) ? FB : (lg == 1) ? EB : (lg == 2) ? GB : selfB;
            u32x4 pv; pv[0] = XA; pv[1] = XB; pv[2] = YA; pv[3] = YB;
            pa[ks] = __builtin_bit_cast(short8, pv);
        }
        __builtin_amdgcn_s_setprio(1);
#pragma unroll
        for (int dt = 0; dt < 4; dt++) {
#pragma unroll
            for (int ks = 0; ks < 2; ks++) {
                int vrow = dt * 16 + lr;
                short8 vf = *reinterpret_cast<const short8*>(
                    Vc + vrow * 64 + (((ks * 4 + lg) ^ (vrow & 7)) << 3));
                O[dt] = __builtin_amdgcn_mfma_f32_16x16x32_bf16(pa[ks], vf, O[dt], 0, 0, 0);
            }
        }
#pragma unroll
        for (int ks = 0; ks < 2; ks++)
            O5 = __builtin_amdgcn_mfma_f32_16x16x32_bf16(pa[ks], vones, O5, 0, 0, 0);
        __builtin_amdgcn_s_setprio(0);
        __syncthreads();
        cur ^= 1;
    }
#pragma unroll
    for (int dt = 0; dt < 4; dt++) {
#pragma unroll
        for (int rg = 0; rg < 4; rg++) {
            int n = n0 + w * 16 + lg * 4 + rg;
            float oo = O[dt][rg] / O5[rg];
            ctx[((size_t)(b * NN) + n) * 1024 + h * 64 + dt * 16 + lr] = f2bf(oo);
        }
    }
}

extern "C" void kernel_launch(void* const* d_in, const int* in_sizes, int n_in,
                              void* d_out, int out_size, void* d_ws, size_t ws_size,
                              hipStream_t stream) {
    const float* x   = (const float*)d_in[0];
    const float* pos = (const float*)d_in[2];
    const float* Wq  = (const float*)d_in[3];
    const float* bq  = (const float*)d_in[4];
    const float* Wk  = (const float*)d_in[5];
    const float* bk  = (const float*)d_in[6];
    const float* Wv  = (const float*)d_in[7];
    const float* bv  = (const float*)d_in[8];
    const float* Wo  = (const float*)d_in[9];
    const float* bo  = (const float*)d_in[10];
    const float* qlw = (const float*)d_in[11];
    const float* qlb = (const float*)d_in[12];
    const float* klw = (const float*)d_in[13];
    const float* klb = (const float*)d_in[14];
    const float* Wp  = (const float*)d_in[15];
    const float* pbu = (const float*)d_in[16];
    const float* pbv = (const float*)d_in[17];
    float* out = (float*)d_out;

    char* ws = (char*)d_ws;
    u16*   xbf   = (u16*)(ws);                      //  8388608 B
    u16*   posbf = (u16*)(ws + 8388608);            //  8388608 B
    u16*   Wbf   = (u16*)(ws + 16777216);           //  5 x 2097152 B (q,k,v,p,o)
    u16*   pre   = (u16*)(ws + 27262976);           //  2 x 8388608 B bf16 (q,k)
    u16*   QQ    = (u16*)(ws + 94371840);           // 16777216 B
    u16*   KK    = (u16*)(ws + 111149056);          // 16777216 B
    u16*   Vt    = (u16*)(ws + 127926272);          //  8388608 B
    u16*   ctx   = (u16*)(ws + 136314880);          //  8388608 B  (total 144703488)

    cast_xpos<<<dim3(4096, 2), 256, 0, stream>>>(x, pos, xbf, posbf);
    cast_w<<<dim3(1024, 5), 256, 0, stream>>>(Wq, Wk, Wv, Wp, Wo, Wbf);

    proj_gemm<<<dim3(8, 32, 4), 256, 0, stream>>>(xbf, posbf, Wbf, pre, Vt, KK, bq, bk, bv);
    post_qk<<<dim3(1024, 2), 256, 0, stream>>>(pre, qlw, qlb, klw, klb, pbu, pbv, QQ, KK);
    flash_attn<<<512, 512, 0, stream>>>(QQ, KK, Vt, ctx);
    out_gemm<<<dim3(8, 32), 256, 0, stream>>>(ctx, Wbf + 4 * 1048576, out, bo);
}

// Round 19
// 210.326 us; speedup vs baseline: 1.0612x; 1.0133x over previous
//
#include <hip/hip_runtime.h>
#include <stdint.h>

// WhaleAttention: B=2 N=2048 C=1024 H=16 D=64
// R19 = R18 (213.1us best) + casts merged into ONE flat-grid launch (7->5 kernels total).
// Flash/proj/post/out_gemm byte-identical to R18.

typedef short short8 __attribute__((ext_vector_type(8)));
typedef float f32x4 __attribute__((ext_vector_type(4)));
typedef unsigned short us4 __attribute__((ext_vector_type(4)));
typedef unsigned int u32x4 __attribute__((ext_vector_type(4)));
typedef unsigned short u16;
typedef unsigned int u32;

#define NB 2
#define NN 2048
#define NC 1024
#define NH 16
#define ND 64

__device__ __forceinline__ u16 f2bf(float f) {
    unsigned int u = __float_as_uint(f);
    u += 0x7fffu + ((u >> 16) & 1u);
    return (u16)(u >> 16);
}
__device__ __forceinline__ float bf2f(u16 v) {
    return __uint_as_float(((u32)v) << 16);
}
__device__ __forceinline__ u32 cvtpk_bf16(float lo, float hi) {
    u32 d;
    asm("v_cvt_pk_bf16_f32 %0, %1, %2" : "=v"(d) : "v"(lo), "v"(hi));
    return d;
}

__device__ __forceinline__ int swzc(int row, int c) {
    return (((c >> 3) ^ (row & 7)) << 3) | (c & 7);
}

__device__ __forceinline__ void gload16(const void* g, void* l) {
    __builtin_amdgcn_global_load_lds(
        (const __attribute__((address_space(1))) unsigned int*)g,
        (__attribute__((address_space(3))) unsigned int*)l, 16, 0, 0);
}

// ---------------- single merged cast launch: x, pos, 5 weights ----------------
__global__ __launch_bounds__(256) void cast_all(const float* __restrict__ x,
                                                const float* __restrict__ pos,
                                                const float* __restrict__ w0,
                                                const float* __restrict__ w1,
                                                const float* __restrict__ w2,
                                                const float* __restrict__ w3,
                                                const float* __restrict__ w4,
                                                u16* __restrict__ dx,
                                                u16* __restrict__ dpos,
                                                u16* __restrict__ dw) {
    int id = blockIdx.x;              // 0..13311
    const float* s;
    u16* d;
    int i;
    if (id < 8192) {                  // x (0..4095), pos (4096..8191): 1048576 float4 each
        s = (id < 4096) ? x : pos;
        d = (id < 4096) ? dx : dpos;
        i = (id & 4095) * 256 + threadIdx.x;
    } else {                          // weights: 5 x 1024 blocks, 262144 float4 each
        int r = id - 8192;
        int z = r >> 10;
        s = (z == 0) ? w0 : (z == 1) ? w1 : (z == 2) ? w2 : (z == 3) ? w3 : w4;
        d = dw + (size_t)z * 1048576;
        i = (r & 1023) * 256 + threadIdx.x;
    }
    float4 f = reinterpret_cast<const float4*>(s)[i];
    us4 o;
    o[0] = f2bf(f.x); o[1] = f2bf(f.y); o[2] = f2bf(f.z); o[3] = f2bf(f.w);
    reinterpret_cast<us4*>(d)[i] = o;
}

// ---------------- GEMM C = A @ W^T (+bias); gload_lds + dbuf ----------------
// epilogue mode: 0 = fp32 out; 1 = bf16 row-major; 2 = Vt direct; 3 = KK[:,64:128] direct
__device__ __forceinline__ void gemm_stage(const u16* __restrict__ A,
                                           const u16* __restrict__ W,
                                           u16* As, u16* Bs,
                                           int m0, int n0, int kk, int w, int lane) {
    int lr4 = lane >> 2, lc8 = (lane & 3) * 8;
#pragma unroll
    for (int i = 0; i < 2; i++) {
        int rbase = w * 32 + i * 16;
        gload16(A + (size_t)(m0 + rbase + lr4) * 1024 + kk + lc8, As + rbase * 32);
        gload16(W + (size_t)(n0 + rbase + lr4) * 1024 + kk + lc8, Bs + rbase * 32);
    }
}

__device__ __forceinline__ void gemm_bt_body(const u16* __restrict__ A,
                                             const u16* __restrict__ W,
                                             float* __restrict__ outF,
                                             u16* __restrict__ outB,
                                             const float* __restrict__ bias,
                                             int m0, int n0, int mode) {
    __shared__ u16 As[2][128 * 32];
    __shared__ u16 Bs[2][128 * 32];
    int t = threadIdx.x, lane = t & 63, w = t >> 6;
    int wm = (w >> 1) * 64, wn = (w & 1) * 64;
    int lr = lane & 15, lg = lane >> 4;
    f32x4 acc[4][4] = {};

    gemm_stage(A, W, As[0], Bs[0], m0, n0, 0, w, lane);
    __syncthreads();
    int cur = 0;
    for (int kt = 0; kt < 32; kt++) {
        if (kt < 31)
            gemm_stage(A, W, As[cur ^ 1], Bs[cur ^ 1], m0, n0, (kt + 1) * 32, w, lane);
        const u16* Ac = As[cur];
        const u16* Bc = Bs[cur];
        short8 af[4], bw[4];
#pragma unroll
        for (int mt = 0; mt < 4; mt++)
            af[mt] = *reinterpret_cast<const short8*>(Ac + (wm + mt * 16 + lr) * 32 + lg * 8);
#pragma unroll
        for (int nt = 0; nt < 4; nt++)
            bw[nt] = *reinterpret_cast<const short8*>(Bc + (wn + nt * 16 + lr) * 32 + lg * 8);
#pragma unroll
        for (int mt = 0; mt < 4; mt++)
#pragma unroll
            for (int nt = 0; nt < 4; nt++)
                acc[mt][nt] = __builtin_amdgcn_mfma_f32_16x16x32_bf16(af[mt], bw[nt], acc[mt][nt], 0, 0, 0);
        __syncthreads();
        cur ^= 1;
    }
#pragma unroll
    for (int mt = 0; mt < 4; mt++) {
#pragma unroll
        for (int nt = 0; nt < 4; nt++) {
            int c = n0 + wn + nt * 16 + lr;
            float badd = bias ? bias[c] : 0.0f;
            int r = m0 + wm + mt * 16 + lg * 4;
#pragma unroll
            for (int rg = 0; rg < 4; rg++) {
                float val = acc[mt][nt][rg] + badd;
                int r2 = r + rg;
                if (mode == 0) {
                    outF[(size_t)r2 * 1024 + c] = val;
                } else if (mode == 1) {
                    outB[(size_t)r2 * 1024 + c] = f2bf(val);
                } else {
                    int b = r2 >> 11, n = r2 & 2047;
                    int h = c >> 6, d = c & 63;
                    u16 vb = f2bf(val);
                    if (mode == 2) {
                        int nsw = (n & ~63) | ((((n >> 3) & 7) ^ (d & 7)) << 3) | (n & 7);
                        outB[((size_t)(b * NH + h)) * 64 * NN + (size_t)d * NN + nsw] = vb;
                    } else {
                        outB[((size_t)(b * NH + h) * NN + n) * 128 + swzc(n, 64 + d)] = vb;
                    }
                }
            }
        }
    }
}

// z=0:q(bq)->pre0 1:k(bk)->pre1 2:v(bv)->Vt direct 3:p->KK[:,64:128] direct
__global__ __launch_bounds__(256) void proj_gemm(const u16* __restrict__ xbf,
                                                 const u16* __restrict__ posbf,
                                                 const u16* __restrict__ Wbase,
                                                 u16* __restrict__ prebase,
                                                 u16* __restrict__ Vt,
                                                 u16* __restrict__ KK,
                                                 const float* __restrict__ bq,
                                                 const float* __restrict__ bk,
                                                 const float* __restrict__ bv) {
    int z = blockIdx.z;
    const u16* A = (z == 3) ? posbf : xbf;
    const u16* W = Wbase + (size_t)z * 1048576;
    u16* outB = (z == 0) ? prebase : (z == 1) ? (prebase + 4194304) : (z == 2) ? Vt : KK;
    const float* bias = (z == 0) ? bq : ((z == 1) ? bk : ((z == 2) ? bv : (const float*)nullptr));
    int mode = (z <= 1) ? 1 : ((z == 2) ? 2 : 3);
    gemm_bt_body(A, W, nullptr, outB, bias, blockIdx.y * 128, blockIdx.x * 128, mode);
}

__global__ __launch_bounds__(256) void out_gemm(const u16* __restrict__ ctx,
                                                const u16* __restrict__ Wo,
                                                float* __restrict__ out,
                                                const float* __restrict__ bo) {
    gemm_bt_body(ctx, Wo, out, nullptr, bo, blockIdx.y * 128, blockIdx.x * 128, 0);
}

// ---------------- LN on bf16 q/k rows; QQ=[s*(q^+u)|s*(q^+v)], KK[:,0:64]=k^ (pre-swizzled) ----------------
__global__ __launch_bounds__(256) void post_qk(const u16* __restrict__ prebase,
                                               const float* __restrict__ qw, const float* __restrict__ qb,
                                               const float* __restrict__ kw, const float* __restrict__ kb,
                                               const float* __restrict__ pbu, const float* __restrict__ pbv,
                                               u16* __restrict__ QQ, u16* __restrict__ KK) {
    const float QSC = 0.125f * 1.44269504089f;
    int isq = (blockIdx.y == 0);
    const u16* pre = prebase + (isq ? 0 : (size_t)4194304);
    const float* lw = isq ? qw : kw;
    const float* lb = isq ? qb : kb;
    int wv = threadIdx.x >> 6, lane = threadIdx.x & 63;
    int row = blockIdx.x * 4 + wv;   // 0..4095
    int b = row >> 11, n = row & 2047;
    const u16* pr = pre + (size_t)row * 1024;
    float vals[16];
    float s = 0.f, s2 = 0.f;
#pragma unroll
    for (int i = 0; i < 2; i++) {
        short8 v8 = *reinterpret_cast<const short8*>(pr + i * 512 + lane * 8);
#pragma unroll
        for (int j = 0; j < 8; j++) {
            float f = bf2f((u16)v8[j]);
            vals[i * 8 + j] = f;
            s += f; s2 += f * f;
        }
    }
#pragma unroll
    for (int m = 1; m < 64; m <<= 1) { s += __shfl_xor(s, m); s2 += __shfl_xor(s2, m); }
    float mean = s * (1.f / 1024.f);
    float var = s2 * (1.f / 1024.f) - mean * mean;
    float inv = rsqrtf(var + 1e-6f);
#pragma unroll
    for (int i = 0; i < 2; i++) {
        int c0 = i * 512 + lane * 8;
        int h = c0 >> 6, d0 = c0 & 63;
        size_t base = ((size_t)(b * NH + h) * NN + n) * 128;
        if (isq) {
            short8 o0, o1;
#pragma unroll
            for (int j = 0; j < 8; j++) {
                float xn = (vals[i * 8 + j] - mean) * inv * lw[c0 + j] + lb[c0 + j];
                o0[j] = (short)f2bf((xn + pbu[h * 64 + d0 + j]) * QSC);
                o1[j] = (short)f2bf((xn + pbv[h * 64 + d0 + j]) * QSC);
            }
            *reinterpret_cast<short8*>(QQ + base + swzc(n, d0)) = o0;
            *reinterpret_cast<short8*>(QQ + base + swzc(n, d0 + 64)) = o1;
        } else {
            short8 o0;
#pragma unroll
            for (int j = 0; j < 8; j++) {
                float xn = (vals[i * 8 + j] - mean) * inv * lw[c0 + j] + lb[c0 + j];
                o0[j] = (short)f2bf(xn);
            }
            *reinterpret_cast<short8*>(KK + base + swzc(n, d0)) = o0;
        }
    }
}

// ---------------- flash attention (R18 body): 8 waves x 16 q-rows, KVBLK=64,
//                  K/V dbuf issue-early, swapped QK^T + in-reg P (cvt_pk), XCD swizzle ----------------
__global__ __launch_bounds__(512, 4) void flash_attn(const u16* __restrict__ QQ,
                                                     const u16* __restrict__ KK,
                                                     const u16* __restrict__ Vt,
                                                     u16* __restrict__ ctx) {
    __shared__ u16 KQs[2 * 64 * 128];
    __shared__ u16 Vts[2 * 64 * 64];
    int id = blockIdx.x;
    int xcd = id & 7;
    int s5 = id >> 3;
    int g = xcd + 8 * (s5 & 3);    // (b*16+h) pinned per XCD
    int qt = s5 >> 2;
    int b = g >> 4, h = g & 15;
    int n0 = qt * 128;
    int t = threadIdx.x, lane = t & 63, w = t >> 6;
    int lr = lane & 15, lg = lane >> 4;
    const char* QQg = (const char*)(QQ + ((size_t)(b * NH + h) * NN) * 128);
    const char* KKg = (const char*)(KK + ((size_t)(b * NH + h) * NN) * 128);
    const char* Vtg = (const char*)(Vt + ((size_t)(b * NH + h) * 64) * NN);

    short8 vones;
#pragma unroll
    for (int i = 0; i < 8; i++) vones[i] = (short)0x3F80;

#pragma unroll
    for (int i = 0; i < 4; i++)
        gload16(QQg + (size_t)n0 * 256 + i * 8192 + w * 1024 + lane * 16,
                (char*)KQs + i * 8192 + w * 1024);
    __syncthreads();
    short8 aq[4];
    {
        int row = w * 16 + lr;
#pragma unroll
        for (int ks = 0; ks < 4; ks++)
            aq[ks] = *reinterpret_cast<const short8*>(
                KQs + row * 128 + (((ks * 4 + lg) ^ (row & 7)) << 3));
    }
    __syncthreads();

#pragma unroll
    for (int i = 0; i < 2; i++)
        gload16(KKg + i * 8192 + w * 1024 + lane * 16, (char*)KQs + i * 8192 + w * 1024);
    gload16(Vtg + (size_t)(w * 8 + (lane >> 3)) * (NN * 2) + (lane & 7) * 16,
            (char*)Vts + w * 1024);
    __syncthreads();

    f32x4 O[4] = {};
    f32x4 O5 = {};
    float mrun = -1e30f;

    int cur = 0;
    for (int tt = 0; tt < 32; tt++) {
        if (tt < 31) {
            int m1 = (tt + 1) * 64;
            int nb = cur ^ 1;
#pragma unroll
            for (int i = 0; i < 2; i++)
                gload16(KKg + (size_t)m1 * 256 + i * 8192 + w * 1024 + lane * 16,
                        (char*)KQs + nb * 16384 + i * 8192 + w * 1024);
            gload16(Vtg + (size_t)(w * 8 + (lane >> 3)) * (NN * 2) + (size_t)m1 * 2 + (lane & 7) * 16,
                    (char*)Vts + nb * 8192 + w * 1024);
        }
        const u16* Kc = KQs + cur * 8192;
        const u16* Vc = Vts + cur * 4096;
        f32x4 S[4];
        __builtin_amdgcn_s_setprio(1);
#pragma unroll
        for (int ct = 0; ct < 4; ct++) {
            f32x4 s = {};
#pragma unroll
            for (int ks = 0; ks < 4; ks++) {
                int row = ct * 16 + lr;
                short8 bk = *reinterpret_cast<const short8*>(
                    Kc + row * 128 + (((ks * 4 + lg) ^ (row & 7)) << 3));
                s = __builtin_amdgcn_mfma_f32_16x16x32_bf16(bk, aq[ks], s, 0, 0, 0);
            }
            S[ct] = s;
        }
        __builtin_amdgcn_s_setprio(0);

        float mx = fmaxf(fmaxf(fmaxf(S[0][0], S[0][1]), fmaxf(S[0][2], S[0][3])),
                         fmaxf(fmaxf(S[1][0], S[1][1]), fmaxf(S[1][2], S[1][3])));
        mx = fmaxf(mx, fmaxf(fmaxf(fmaxf(S[2][0], S[2][1]), fmaxf(S[2][2], S[2][3])),
                             fmaxf(fmaxf(S[3][0], S[3][1]), fmaxf(S[3][2], S[3][3]))));
        mx = fmaxf(mx, __shfl_xor(mx, 16));
        mx = fmaxf(mx, __shfl_xor(mx, 32));
        if (__any(mx > mrun + 8.f)) {
            float newm = fmaxf(mrun, mx);
            float sf = exp2f(mrun - newm);
            mrun = newm;
            float sfq[4];
#pragma unroll
            for (int rg = 0; rg < 4; rg++)
                sfq[rg] = __shfl(sf, 4 * lg + rg);
#pragma unroll
            for (int rg = 0; rg < 4; rg++) {
                float s4 = sfq[rg];
#pragma unroll
                for (int dt = 0; dt < 4; dt++) O[dt][rg] *= s4;
                O5[rg] *= s4;
            }
        }
        // P = exp2(S - mrun) packed via v_cvt_pk_bf16_f32 (RNE)
        u32 dA[4], dB[4];
#pragma unroll
        for (int ct = 0; ct < 4; ct++) {
            float e0 = exp2f(S[ct][0] - mrun);
            float e1 = exp2f(S[ct][1] - mrun);
            float e2 = exp2f(S[ct][2] - mrun);
            float e3 = exp2f(S[ct][3] - mrun);
            dA[ct] = cvtpk_bf16(e0, e1);
            dB[ct] = cvtpk_bf16(e2, e3);
        }
        int lgh = lg >> 1;
        short8 pa[2];
#pragma unroll
        for (int ks = 0; ks < 2; ks++) {
            u32 selfA = lgh ? dA[2 * ks + 1] : dA[2 * ks];
            u32 selfB = lgh ? dB[2 * ks + 1] : dB[2 * ks];
            u32 crossA = lgh ? dA[2 * ks] : dA[2 * ks + 1];
            u32 crossB = lgh ? dB[2 * ks] : dB[2 * ks + 1];
            u32 FA = (u32)__shfl_xor((int)selfA, 16);
            u32 FB = (u32)__shfl_xor((int)selfB, 16);
            u32 EA = (u32)__shfl_xor((int)crossA, 32);
            u32 EB = (u32)__shfl_xor((int)crossB, 32);
            u32 GA = (u32)__shfl_xor((int)EA, 16);
            u32 GB = (u32)__shfl_xor((int)EB, 16);
            u32 XA = (lg == 0) ? selfA : (lg == 1) ? GA : (lg == 2) ? EA : FA;
            u32 XB = (lg == 0) ? selfB : (lg == 1) ? GB : (lg == 2) ? EB : FB;
            u32 YA = (lg == 0) ? FA : (lg == 1) ? EA : (lg == 2) ? GA : selfA;
            u32 YB = (lg == 0) ? FB : (lg == 1) ? EB : (lg == 2) ? GB : selfB;
            u32x4 pv; pv[0] = XA; pv[1] = XB; pv[2] = YA; pv[3] = YB;
            pa[ks] = __builtin_bit_cast(short8, pv);
        }
        __builtin_amdgcn_s_setprio(1);
#pragma unroll
        for (int dt = 0; dt < 4; dt++) {
#pragma unroll
            for (int ks = 0; ks < 2; ks++) {
                int vrow = dt * 16 + lr;
                short8 vf = *reinterpret_cast<const short8*>(
                    Vc + vrow * 64 + (((ks * 4 + lg) ^ (vrow & 7)) << 3));
                O[dt] = __builtin_amdgcn_mfma_f32_16x16x32_bf16(pa[ks], vf, O[dt], 0, 0, 0);
            }
        }
#pragma unroll
        for (int ks = 0; ks < 2; ks++)
            O5 = __builtin_amdgcn_mfma_f32_16x16x32_bf16(pa[ks], vones, O5, 0, 0, 0);
        __builtin_amdgcn_s_setprio(0);
        __syncthreads();
        cur ^= 1;
    }
#pragma unroll
    for (int dt = 0; dt < 4; dt++) {
#pragma unroll
        for (int rg = 0; rg < 4; rg++) {
            int n = n0 + w * 16 + lg * 4 + rg;
            float oo = O[dt][rg] / O5[rg];
            ctx[((size_t)(b * NN) + n) * 1024 + h * 64 + dt * 16 + lr] = f2bf(oo);
        }
    }
}

extern "C" void kernel_launch(void* const* d_in, const int* in_sizes, int n_in,
                              void* d_out, int out_size, void* d_ws, size_t ws_size,
                              hipStream_t stream) {
    const float* x   = (const float*)d_in[0];
    const float* pos = (const float*)d_in[2];
    const float* Wq  = (const float*)d_in[3];
    const float* bq  = (const float*)d_in[4];
    const float* Wk  = (const float*)d_in[5];
    const float* bk  = (const float*)d_in[6];
    const float* Wv  = (const float*)d_in[7];
    const float* bv  = (const float*)d_in[8];
    const float* Wo  = (const float*)d_in[9];
    const float* bo  = (const float*)d_in[10];
    const float* qlw = (const float*)d_in[11];
    const float* qlb = (const float*)d_in[12];
    const float* klw = (const float*)d_in[13];
    const float* klb = (const float*)d_in[14];
    const float* Wp  = (const float*)d_in[15];
    const float* pbu = (const float*)d_in[16];
    const float* pbv = (const float*)d_in[17];
    float* out = (float*)d_out;

    char* ws = (char*)d_ws;
    u16*   xbf   = (u16*)(ws);                      //  8388608 B
    u16*   posbf = (u16*)(ws + 8388608);            //  8388608 B
    u16*   Wbf   = (u16*)(ws + 16777216);           //  5 x 2097152 B (q,k,v,p,o)
    u16*   pre   = (u16*)(ws + 27262976);           //  2 x 8388608 B bf16 (q,k)
    u16*   QQ    = (u16*)(ws + 94371840);           // 16777216 B
    u16*   KK    = (u16*)(ws + 111149056);          // 16777216 B
    u16*   Vt    = (u16*)(ws + 127926272);          //  8388608 B
    u16*   ctx   = (u16*)(ws + 136314880);          //  8388608 B  (total 144703488)

    cast_all<<<13312, 256, 0, stream>>>(x, pos, Wq, Wk, Wv, Wp, Wo, xbf, posbf, Wbf);
    proj_gemm<<<dim3(8, 32, 4), 256, 0, stream>>>(xbf, posbf, Wbf, pre, Vt, KK, bq, bk, bv);
    post_qk<<<dim3(1024, 2), 256, 0, stream>>>(pre, qlw, qlb, klw, klb, pbu, pbv, QQ, KK);
    flash_attn<<<512, 512, 0, stream>>>(QQ, KK, Vt, ctx);
    out_gemm<<<dim3(8, 32), 256, 0, stream>>>(ctx, Wbf + 4 * 1048576, out, bo);
}